// Round 17
// baseline (267.244 us; speedup 1.0000x reference)
//
#include <hip/hip_runtime.h>
#include <hip/hip_bf16.h>
#include <stdint.h>

typedef __attribute__((ext_vector_type(8))) short short8;
typedef __attribute__((ext_vector_type(4))) float floatx4;
typedef __attribute__((ext_vector_type(16))) float floatx16;

#define MFMA16(a, b, c) __builtin_amdgcn_mfma_f32_16x16x32_bf16(a, b, c, 0, 0, 0)
#define MFMA32(a, b, c) __builtin_amdgcn_mfma_f32_32x32x16_bf16(a, b, c, 0, 0, 0)

static __device__ __forceinline__ void gload_lds16(const __hip_bfloat16* g, __hip_bfloat16* l) {
  __builtin_amdgcn_global_load_lds(
      (const __attribute__((address_space(1))) void*)g,
      (__attribute__((address_space(3))) void*)l,
      16, 0, 0);
}

// ---------------- all fp32 -> bf16 converts, one launch (row-major outputs) ----------------
__global__ __launch_bounds__(256)
void f2bf_all(const float* __restrict__ h, const float* __restrict__ wq,
              const float* __restrict__ wk, const float* __restrict__ wv,
              const float* __restrict__ wo, __hip_bfloat16* __restrict__ hb,
              __hip_bfloat16* __restrict__ wqkv, __hip_bfloat16* __restrict__ wob) {
  const int blk = blockIdx.x;
  const float* src;
  __hip_bfloat16* dst;
  int off;
  if (blk < 8192)       { src = h;  dst = hb;                          off = blk; }
  else if (blk < 12288) { src = wq; dst = wqkv;                        off = blk - 8192; }
  else if (blk < 13312) { src = wk; dst = wqkv + (size_t)2048 * 2048;  off = blk - 12288; }
  else if (blk < 14336) { src = wv; dst = wqkv + (size_t)2560 * 2048;  off = blk - 13312; }
  else                  { src = wo; dst = wob;                         off = blk - 14336; }
  const int i = off * 1024 + threadIdx.x * 4;
  const float4 v = *(const float4*)(src + i);
  __hip_bfloat16 t[4] = {__float2bfloat16(v.x), __float2bfloat16(v.y),
                         __float2bfloat16(v.z), __float2bfloat16(v.w)};
  *(short4*)(dst + i) = *(const short4*)t;
}

// ---------------- GEMM: C = A @ Bt^T  (A: MxK, Bt: NxK, both bf16 row-major) ----------------
// XOR-blocked LDS (conflict-free ds_read_b128, r13-validated) + 3-buffer counted-vmcnt
// pipeline (raw barriers, loads in flight across barrier). NO XCD swizzle (r13's poison).
template <typename OUT_T>
__global__ __launch_bounds__(256)
void gemm_bt(const __hip_bfloat16* __restrict__ A, const __hip_bfloat16* __restrict__ Bt,
             OUT_T* __restrict__ C, int M, int N, int K) {
  __shared__ short LDS[3 * 8192];  // per buf: A [128 rows][32 k] @0, B @4096 (shorts), XOR-slotted

  const int tid = threadIdx.x;
  const int wid = tid >> 6, lane = tid & 63;
  const int lg = lane >> 4, lr = lane & 15;
  const int wr = wid >> 1, wc = wid & 1;
  const int m0 = blockIdx.x * 128, n0 = blockIdx.y * 128;
  const int nk = K >> 5;

  // frag-read XOR term (lane-constant): slot = lg ^ ((row>>1)&3), row = R0 + lr, R0 % 16 == 0
  const int axor = (lg ^ ((lr >> 1) & 3)) * 8;

  floatx4 acc[4][4];
#pragma unroll
  for (int mi = 0; mi < 4; ++mi)
#pragma unroll
    for (int ni = 0; ni < 4; ++ni) acc[mi][ni] = (floatx4)(0.0f);

  // stage K-tile kt into buffer buf. chunk c = row*4 + gs; dest linear (c*16B);
  // source k-group g' = gs ^ ((row>>1)&3) -> per-4-lane contiguous 64B row segments.
  auto stage = [&](int buf, int kt) {
    const int k0 = kt << 5;
    short* dst = &LDS[buf * 8192];
#pragma unroll
    for (int i = 0; i < 2; ++i) {
      const int c = i * 256 + tid;
      const int row = c >> 2;
      const int gp = (c & 3) ^ ((row >> 1) & 3);
      gload_lds16(A + (size_t)(m0 + row) * K + k0 + gp * 8, (__hip_bfloat16*)(dst + c * 8));
    }
#pragma unroll
    for (int i = 0; i < 2; ++i) {
      const int c = i * 256 + tid;
      const int row = c >> 2;
      const int gp = (c & 3) ^ ((row >> 1) & 3);
      gload_lds16(Bt + (size_t)(n0 + row) * K + k0 + gp * 8,
                  (__hip_bfloat16*)(dst + 4096 + c * 8));
    }
  };

  auto compute = [&](int buf) {
    const short* base = &LDS[buf * 8192];
    short8 af[4], bfr[4];
#pragma unroll
    for (int mi = 0; mi < 4; ++mi) {
      const int row = wr * 64 + mi * 16 + lr;
      af[mi] = *(const short8*)&base[row * 32 + axor];
    }
#pragma unroll
    for (int ni = 0; ni < 4; ++ni) {
      const int row = wc * 64 + ni * 16 + lr;
      bfr[ni] = *(const short8*)&base[4096 + row * 32 + axor];
    }
#pragma unroll
    for (int mi = 0; mi < 4; ++mi)
#pragma unroll
      for (int ni = 0; ni < 4; ++ni) acc[mi][ni] = MFMA16(af[mi], bfr[ni], acc[mi][ni]);
  };

  // prologue: prefetch tiles 0 and 1
  stage(0, 0);
  stage(1, 1);
  asm volatile("s_waitcnt vmcnt(4)" ::: "memory");  // tile 0 landed; tile 1 in flight
  __builtin_amdgcn_s_barrier();
  __builtin_amdgcn_sched_barrier(0);

  for (int kt = 0; kt < nk; ++kt) {
    if (kt + 2 < nk) {
      stage((kt + 2) % 3, kt + 2);
      compute(kt % 3);
      asm volatile("s_waitcnt vmcnt(4)" ::: "memory");  // tile kt+1 landed; kt+2 in flight
    } else {
      compute(kt % 3);
      asm volatile("s_waitcnt vmcnt(0)" ::: "memory");
    }
    __builtin_amdgcn_s_barrier();
    __builtin_amdgcn_sched_barrier(0);
  }

#pragma unroll
  for (int mi = 0; mi < 4; ++mi)
#pragma unroll
    for (int ni = 0; ni < 4; ++ni) {
      const int row = m0 + wr * 64 + mi * 16 + lg * 4;
      const int col = n0 + wc * 64 + ni * 16 + lr;
#pragma unroll
      for (int r = 0; r < 4; ++r) {
        C[(size_t)(row + r) * N + col] = (OUT_T)acc[mi][ni][r];
      }
    }
}

// ---------------- RMSNorm + RoPE; Q scaled by log2e/sqrt(128); K written BLOCKED ----------------
// Kblk per (z = b*4+hkv): [tile 64][cd 16][kv 32][e 8] shorts; K[kv][d], d = 8*cd + e.
__global__ __launch_bounds__(256)
void normrope(const __hip_bfloat16* __restrict__ qkv, const float* __restrict__ cosb,
              const float* __restrict__ sinb, const float* __restrict__ qw,
              const float* __restrict__ kw, __hip_bfloat16* __restrict__ Q,
              __hip_bfloat16* __restrict__ Kblk) {
  const int m = blockIdx.x;            // b*2048 + s
  const int b = m >> 11, s = m & 2047;
  const int wid = threadIdx.x >> 6, lane = threadIdx.x & 63;
  const size_t qkvrow = (size_t)m * 3072;
  const float c1 = cosb[(size_t)m * 128 + lane], s1 = sinb[(size_t)m * 128 + lane];
  const float c2 = cosb[(size_t)m * 128 + lane + 64], s2 = sinb[(size_t)m * 128 + lane + 64];
  const float QS = 0.12753102497113446f;  // log2(e)/sqrt(128), folded into Q
  for (int h = wid * 5; h < wid * 5 + 5; ++h) {
    const float x1 = __bfloat162float(qkv[qkvrow + h * 128 + lane]);
    const float x2 = __bfloat162float(qkv[qkvrow + h * 128 + lane + 64]);
    float ss = x1 * x1 + x2 * x2;
    ss += __shfl_xor(ss, 1);  ss += __shfl_xor(ss, 2);  ss += __shfl_xor(ss, 4);
    ss += __shfl_xor(ss, 8);  ss += __shfl_xor(ss, 16); ss += __shfl_xor(ss, 32);
    const float rs = rsqrtf(ss * (1.0f / 128.0f) + 1e-6f);
    const float* w = (h < 16) ? qw : kw;
    const float n1 = x1 * rs * w[lane], n2 = x2 * rs * w[lane + 64];
    const float o1 = n1 * c1 - n2 * s1;
    const float o2 = n2 * c2 + n1 * s2;
    if (h < 16) {
      const size_t base = ((size_t)(b * 16 + h) * 2048 + s) * 128;
      Q[base + lane] = __float2bfloat16(o1 * QS);
      Q[base + lane + 64] = __float2bfloat16(o2 * QS);
    } else {
      const int z = b * 4 + (h - 16);
      const int t = s >> 5, kv = s & 31;
      const size_t base =
          (size_t)z * 262144 + t * 4096 + (lane >> 3) * 256 + kv * 8 + (lane & 7);
      Kblk[base] = __float2bfloat16(o1);         // d = lane
      Kblk[base + 2048] = __float2bfloat16(o2);  // d = lane + 64 (cd += 8)
    }
  }
}

// ---------------- V -> transposed, kv-permuted, blocked (KVBLK=32) ----------------
// Vt2 per z: [tile 64][c 4][d 128][e 8] shorts; entry (c,d,e) = V^T[d][phys(8c+e)] of tile.
// perm within 32-block: pb -> (pb&3) + ((pb>>2)&1)*8 + ((pb>>3)&1)*4 + (pb&16)
__global__ __launch_bounds__(256)
void vtrans2(const __hip_bfloat16* __restrict__ qkv, __hip_bfloat16* __restrict__ Vt2) {
  __shared__ short L[64 * 65];  // [d_local][s_local]
  const int tid = threadIdx.x;
  const int t = blockIdx.x, d0 = blockIdx.y * 64, z = blockIdx.z;
  const int b = z >> 2, hkv = z & 3;
  const int s0 = t * 64;
#pragma unroll
  for (int i = 0; i < 2; ++i) {
    const int slot = i * 256 + tid;
    const int srow = slot >> 3, c8 = (slot & 7) * 8;
    const short8 v = *(const short8*)((const short*)qkv +
        (size_t)(b * 2048 + s0 + srow) * 3072 + 2560 + hkv * 128 + d0 + c8);
#pragma unroll
    for (int j = 0; j < 8; ++j) L[(c8 + j) * 65 + srow] = v[j];
  }
  __syncthreads();
  short* dst = (short*)Vt2 + (size_t)z * 262144 + t * 8192;  // 2 kv-tiles per block
#pragma unroll
  for (int i = 0; i < 2; ++i) {
    const int slot = i * 256 + tid;
    const int drow = slot >> 3, sc8 = (slot & 7) * 8;
    short8 o;
#pragma unroll
    for (int j = 0; j < 8; ++j) {
      const int p = sc8 + j;
      const int pb = p & 31;
      const int phys = (pb & 3) + ((pb >> 2) & 1) * 8 + ((pb >> 3) & 1) * 4 + (pb & 16);
      o[j] = L[drow * 65 + (p & 32) + phys];
    }
    const int addr = (sc8 >> 5) * 4096 + ((sc8 & 31) >> 3) * 1024 + (d0 + drow) * 8;
    *(short8*)&dst[addr] = o;
  }
}

// ---------------- Flash attention (r15 structure, unchanged) ----------------
__global__ __launch_bounds__(256, 3)
void fattn(const __hip_bfloat16* __restrict__ Qg, const __hip_bfloat16* __restrict__ Kb2,
           const __hip_bfloat16* __restrict__ Vt2, __hip_bfloat16* __restrict__ Og) {
  __shared__ short SMEM[17408];  // K0@0 K1@4096 V0@8192 V1@12288 shorts; tw reuses [0,17408)

  const int tid = threadIdx.x, wid = tid >> 6, lane = tid & 63;
  const int l31 = lane & 31, hi = lane >> 5;
  const int qt = blockIdx.x, bh = blockIdx.y;
  const int b = bh >> 4, h = bh & 15, hkv = h >> 2;
  const int z = b * 4 + hkv;
  const int q0w = qt * 128 + wid * 32;

  const __hip_bfloat16* Qrow = Qg + ((size_t)((b * 16 + h) * 2048 + q0w + l31)) * 128;
  short8 qf2[8];
#pragma unroll
  for (int ks = 0; ks < 8; ++ks) qf2[ks] = *(const short8*)(Qrow + ks * 16 + hi * 8);

  const short* Kbase = (const short*)Kb2 + (size_t)z * 262144;
  const short* Vbase = (const short*)Vt2 + (size_t)z * 262144;

  auto stageK = [&](int buf, int t) {
    const short* ks = Kbase + t * 4096 + tid * 8;
    short* kd = &SMEM[buf * 4096 + tid * 8];
    gload_lds16((const __hip_bfloat16*)ks, (__hip_bfloat16*)kd);
    gload_lds16((const __hip_bfloat16*)(ks + 2048), (__hip_bfloat16*)(kd + 2048));
  };
  auto stageV = [&](int buf, int t) {
    const short* vs = Vbase + t * 4096 + tid * 8;
    short* vd = &SMEM[8192 + buf * 4096 + tid * 8];
    gload_lds16((const __hip_bfloat16*)vs, (__hip_bfloat16*)vd);
    gload_lds16((const __hip_bfloat16*)(vs + 2048), (__hip_bfloat16*)(vd + 2048));
  };

  floatx16 oacc[4];
#pragma unroll
  for (int dblk = 0; dblk < 4; ++dblk) oacc[dblk] = (floatx16)(0.0f);
  float la0 = 0.0f, la1 = 0.0f;

  int pkA[8], pkB[8];

  auto doQK = [&](int kbuf, floatx16& st) {
    const short* Kt = &SMEM[kbuf * 4096];
    st = (floatx16)(0.0f);
    __builtin_amdgcn_s_setprio(1);
#pragma unroll
    for (int ks = 0; ks < 8; ++ks) {
      const short8 kf = *(const short8*)&Kt[(2 * ks + hi) * 256 + l31 * 8];
      st = MFMA32(kf, qf2[ks], st);
    }
    __builtin_amdgcn_s_setprio(0);
  };
  auto doExp = [&](const floatx16& st, int (&pk)[8]) {
#pragma unroll
    for (int m = 0; m < 8; ++m) {
      const float e0 = exp2f(st[2 * m]);
      const float e1 = exp2f(st[2 * m + 1]);
      if (m & 1) la1 += e0 + e1; else la0 += e0 + e1;
      asm("v_cvt_pk_bf16_f32 %0, %1, %2" : "=v"(pk[m]) : "v"(e0), "v"(e1));
    }
  };
  auto doPV = [&](int vbuf, const int (&pk)[8]) {
    const short* Vt = &SMEM[8192 + vbuf * 4096];
#pragma unroll
    for (int s = 0; s < 2; ++s) {
      union { int i[4]; short8 s8; } u;
      u.i[0] = pk[4 * s + 0];
      u.i[1] = pk[4 * s + 1];
      u.i[2] = pk[4 * s + 2];
      u.i[3] = pk[4 * s + 3];
      const short8 pB = u.s8;
      const int c = s * 2 + hi;
      __builtin_amdgcn_s_setprio(1);
#pragma unroll
      for (int dblk = 0; dblk < 4; ++dblk) {
        const short8 vf = *(const short8*)&Vt[c * 1024 + dblk * 256 + l31 * 8];
        oacc[dblk] = MFMA32(vf, pB, oacc[dblk]);
      }
      __builtin_amdgcn_s_setprio(0);
    }
  };

  auto body = [&](int (&pkPrev)[8], int (&pkCur)[8], int u) {
    if (u + 1 < 64) stageK((u + 1) & 1, u + 1);
    stageV(u & 1, u);
    floatx16 st;
    doQK(u & 1, st);
    doPV((u - 1) & 1, pkPrev);
    doExp(st, pkCur);
    asm volatile("s_waitcnt vmcnt(0)" ::: "memory");
    __builtin_amdgcn_s_barrier();
    __builtin_amdgcn_sched_barrier(0);
  };

  stageK(0, 0);
  asm volatile("s_waitcnt vmcnt(0)" ::: "memory");
  __builtin_amdgcn_s_barrier();
  __builtin_amdgcn_sched_barrier(0);
  {
    stageK(1, 1);
    stageV(0, 0);
    floatx16 st;
    doQK(0, st);
    doExp(st, pkA);
    asm volatile("s_waitcnt vmcnt(0)" ::: "memory");
    __builtin_amdgcn_s_barrier();
    __builtin_amdgcn_sched_barrier(0);
  }

  for (int u = 1; u < 63; u += 2) {
    body(pkA, pkB, u);
    body(pkB, pkA, u + 1);
  }
  body(pkA, pkB, 63);
  doPV(1, pkB);

  asm volatile("s_waitcnt lgkmcnt(0)" ::: "memory");
  __builtin_amdgcn_s_barrier();

  const float l_own = la0 + la1;
  const float l = l_own + __shfl_xor(l_own, 32);
  const float inv = 1.0f / l;
  short* tw = &SMEM[wid * 4352];  // [32 q][136 d-padded]
#pragma unroll
  for (int dblk = 0; dblk < 4; ++dblk)
#pragma unroll
    for (int a = 0; a < 4; ++a) {
      __hip_bfloat16 o4[4];
#pragma unroll
      for (int r = 0; r < 4; ++r) o4[r] = __float2bfloat16(oacc[dblk][4 * a + r] * inv);
      *(short4*)&tw[l31 * 136 + dblk * 32 + a * 8 + hi * 4] = *(const short4*)o4;
    }
  __hip_bfloat16* orow =
      Og + ((size_t)(b * 2048 + q0w + (lane >> 1))) * 2048 + h * 128 + (lane & 1) * 64;
  const short* trow = &tw[(lane >> 1) * 136 + (lane & 1) * 64];
#pragma unroll
  for (int c = 0; c < 8; ++c) {
    *(short8*)(orow + c * 8) = *(const short8*)(trow + c * 8);
  }
}

// ---------------- launch ----------------
extern "C" void kernel_launch(void* const* d_in, const int* in_sizes, int n_in,
                              void* d_out, int out_size, void* d_ws, size_t ws_size,
                              hipStream_t stream) {
  const float* hidden = (const float*)d_in[0];
  const float* cosb = (const float*)d_in[1];
  const float* sinb = (const float*)d_in[2];
  const float* Wq = (const float*)d_in[3];
  const float* Wk = (const float*)d_in[4];
  const float* Wv = (const float*)d_in[5];
  const float* Wo = (const float*)d_in[6];
  const float* qw = (const float*)d_in[7];
  const float* kw = (const float*)d_in[8];

  char* ws = (char*)d_ws;
  __hip_bfloat16* hidden_bf = (__hip_bfloat16*)ws; ws += (size_t)4096 * 2048 * 2;
  __hip_bfloat16* wqkv = (__hip_bfloat16*)ws;      ws += (size_t)3072 * 2048 * 2;
  __hip_bfloat16* wo_bf = (__hip_bfloat16*)ws;     ws += (size_t)2048 * 2048 * 2;
  __hip_bfloat16* qkv = (__hip_bfloat16*)ws;       ws += (size_t)4096 * 3072 * 2;
  __hip_bfloat16* Qb = (__hip_bfloat16*)ws;        ws += (size_t)2 * 16 * 2048 * 128 * 2;
  __hip_bfloat16* Kblk = (__hip_bfloat16*)ws;      ws += (size_t)2 * 4 * 2048 * 128 * 2;
  __hip_bfloat16* attn = (__hip_bfloat16*)ws;      ws += (size_t)4096 * 2048 * 2;
  // Vt2 aliases wqkv (dead after gemm1; rewritten by f2bf_all every call -> deterministic)
  __hip_bfloat16* Vt2 = wqkv;

  f2bf_all<<<18432, 256, 0, stream>>>(hidden, Wq, Wk, Wv, Wo, hidden_bf, wqkv, wo_bf);

  gemm_bt<__hip_bfloat16><<<dim3(32, 24), 256, 0, stream>>>(hidden_bf, wqkv, qkv, 4096, 3072, 2048);
  normrope<<<4096, 256, 0, stream>>>(qkv, cosb, sinb, qw, kw, Qb, Kblk);
  vtrans2<<<dim3(32, 2, 8), 256, 0, stream>>>(qkv, Vt2);
  fattn<<<dim3(16, 32), 256, 0, stream>>>(Qb, Kblk, Vt2, attn);
  gemm_bt<float><<<dim3(32, 16), 256, 0, stream>>>(attn, wo_bf, (float*)d_out, 4096, 2048, 2048);
}

// Round 18
// 229.161 us; speedup vs baseline: 1.1662x; 1.1662x over previous
//
#include <hip/hip_runtime.h>
#include <hip/hip_bf16.h>
#include <stdint.h>

typedef __attribute__((ext_vector_type(8))) short short8;
typedef __attribute__((ext_vector_type(4))) float floatx4;
typedef __attribute__((ext_vector_type(16))) float floatx16;

#define MFMA16(a, b, c) __builtin_amdgcn_mfma_f32_16x16x32_bf16(a, b, c, 0, 0, 0)
#define MFMA32(a, b, c) __builtin_amdgcn_mfma_f32_32x32x16_bf16(a, b, c, 0, 0, 0)

static __device__ __forceinline__ void gload_lds16(const __hip_bfloat16* g, __hip_bfloat16* l) {
  __builtin_amdgcn_global_load_lds(
      (const __attribute__((address_space(1))) void*)g,
      (__attribute__((address_space(3))) void*)l,
      16, 0, 0);
}

// ---------------- all fp32 -> bf16 converts, one launch ----------------
__global__ __launch_bounds__(256)
void f2bf_all(const float* __restrict__ h, const float* __restrict__ wq,
              const float* __restrict__ wk, const float* __restrict__ wv,
              const float* __restrict__ wo, __hip_bfloat16* __restrict__ hb,
              __hip_bfloat16* __restrict__ wqkv, __hip_bfloat16* __restrict__ wob) {
  const int blk = blockIdx.x;
  const float* src;
  __hip_bfloat16* dst;
  int off;
  if (blk < 8192)       { src = h;  dst = hb;                          off = blk; }
  else if (blk < 12288) { src = wq; dst = wqkv;                        off = blk - 8192; }
  else if (blk < 13312) { src = wk; dst = wqkv + (size_t)2048 * 2048;  off = blk - 12288; }
  else if (blk < 14336) { src = wv; dst = wqkv + (size_t)2560 * 2048;  off = blk - 13312; }
  else                  { src = wo; dst = wob;                         off = blk - 14336; }
  const int i = off * 1024 + threadIdx.x * 4;
  const float4 v = *(const float4*)(src + i);
  __hip_bfloat16 t[4] = {__float2bfloat16(v.x), __float2bfloat16(v.y),
                         __float2bfloat16(v.z), __float2bfloat16(v.w)};
  *(short4*)(dst + i) = *(const short4*)t;
}

// ---------------- GEMM: C = A @ Bt^T  (A: MxK, Bt: NxK, both bf16 row-major) ----------------
template <typename OUT_T>
__global__ __launch_bounds__(256)
void gemm_bt(const __hip_bfloat16* __restrict__ A, const __hip_bfloat16* __restrict__ Bt,
             OUT_T* __restrict__ C, int M, int N, int K) {
  __shared__ __hip_bfloat16 As[2][128 * 32];
  __shared__ __hip_bfloat16 Bs[2][128 * 32];
  const int tid = threadIdx.x;
  const int wid = tid >> 6, lane = tid & 63;
  const int lg = lane >> 4, lr = lane & 15;
  const int wr = wid >> 1, wc = wid & 1;
  const int m0 = blockIdx.x * 128, n0 = blockIdx.y * 128;
  const int nk = K >> 5;

  floatx4 acc[4][4];
#pragma unroll
  for (int mi = 0; mi < 4; ++mi)
#pragma unroll
    for (int ni = 0; ni < 4; ++ni) acc[mi][ni] = (floatx4)(0.0f);

  auto stage = [&](int buf, int kt) {
    const int k0 = kt << 5;
#pragma unroll
    for (int i = 0; i < 2; ++i) {
      const int e = (i * 256 + tid) * 8;
      const int row = e >> 5, col = e & 31;
      gload_lds16(A + (size_t)(m0 + row) * K + k0 + col, &As[buf][e]);
    }
#pragma unroll
    for (int i = 0; i < 2; ++i) {
      const int e = (i * 256 + tid) * 8;
      const int row = e >> 5, col = e & 31;
      gload_lds16(Bt + (size_t)(n0 + row) * K + k0 + col, &Bs[buf][e]);
    }
  };

  stage(0, 0);
  __syncthreads();

  for (int kt = 0; kt < nk; ++kt) {
    const int cur = kt & 1;
    if (kt + 1 < nk) stage(cur ^ 1, kt + 1);
    short8 af[4], bfr[4];
#pragma unroll
    for (int mi = 0; mi < 4; ++mi)
      af[mi] = *(const short8*)&As[cur][(wr * 64 + mi * 16 + lr) * 32 + lg * 8];
#pragma unroll
    for (int ni = 0; ni < 4; ++ni)
      bfr[ni] = *(const short8*)&Bs[cur][(wc * 64 + ni * 16 + lr) * 32 + lg * 8];
#pragma unroll
    for (int mi = 0; mi < 4; ++mi)
#pragma unroll
      for (int ni = 0; ni < 4; ++ni) acc[mi][ni] = MFMA16(af[mi], bfr[ni], acc[mi][ni]);
    __syncthreads();
  }

#pragma unroll
  for (int mi = 0; mi < 4; ++mi)
#pragma unroll
    for (int ni = 0; ni < 4; ++ni) {
      const int row = m0 + wr * 64 + mi * 16 + lg * 4;
      const int col = n0 + wc * 64 + ni * 16 + lr;
#pragma unroll
      for (int r = 0; r < 4; ++r) {
        C[(size_t)(row + r) * N + col] = (OUT_T)acc[mi][ni][r];
      }
    }
}

// ---------------- RMSNorm + RoPE; Q scaled by log2e/sqrt(128); K written BLOCKED ----------------
// Kblk per (z = b*4+hkv): [tile 32][cd 16][kv 64][e 8] shorts; K[kv][d], d = 8*cd + e.
__global__ __launch_bounds__(256)
void normrope(const __hip_bfloat16* __restrict__ qkv, const float* __restrict__ cosb,
              const float* __restrict__ sinb, const float* __restrict__ qw,
              const float* __restrict__ kw, __hip_bfloat16* __restrict__ Q,
              __hip_bfloat16* __restrict__ Kblk) {
  const int m = blockIdx.x;            // b*2048 + s
  const int b = m >> 11, s = m & 2047;
  const int wid = threadIdx.x >> 6, lane = threadIdx.x & 63;
  const size_t qkvrow = (size_t)m * 3072;
  const float c1 = cosb[(size_t)m * 128 + lane], s1 = sinb[(size_t)m * 128 + lane];
  const float c2 = cosb[(size_t)m * 128 + lane + 64], s2 = sinb[(size_t)m * 128 + lane + 64];
  const float QS = 0.12753102497113446f;  // log2(e)/sqrt(128), folded into Q
  for (int h = wid * 5; h < wid * 5 + 5; ++h) {
    const float x1 = __bfloat162float(qkv[qkvrow + h * 128 + lane]);
    const float x2 = __bfloat162float(qkv[qkvrow + h * 128 + lane + 64]);
    float ss = x1 * x1 + x2 * x2;
    ss += __shfl_xor(ss, 1);  ss += __shfl_xor(ss, 2);  ss += __shfl_xor(ss, 4);
    ss += __shfl_xor(ss, 8);  ss += __shfl_xor(ss, 16); ss += __shfl_xor(ss, 32);
    const float rs = rsqrtf(ss * (1.0f / 128.0f) + 1e-6f);
    const float* w = (h < 16) ? qw : kw;
    const float n1 = x1 * rs * w[lane], n2 = x2 * rs * w[lane + 64];
    const float o1 = n1 * c1 - n2 * s1;
    const float o2 = n2 * c2 + n1 * s2;
    if (h < 16) {
      const size_t base = ((size_t)(b * 16 + h) * 2048 + s) * 128;
      Q[base + lane] = __float2bfloat16(o1 * QS);
      Q[base + lane + 64] = __float2bfloat16(o2 * QS);
    } else {
      const int z = b * 4 + (h - 16);
      const int t = s >> 6, kv = s & 63;
      const size_t base =
          (size_t)z * 262144 + t * 8192 + (lane >> 3) * 512 + kv * 8 + (lane & 7);
      Kblk[base] = __float2bfloat16(o1);         // d = lane
      Kblk[base + 4096] = __float2bfloat16(o2);  // d = lane + 64 (cd += 8)
    }
  }
}

// ---------------- V: from qkv (cols 2560..3071) -> transposed, kv-permuted, blocked ----------------
// Vt2 per z: [tile 32][c 8][d 128][e 8] shorts; entry (c,d,e) = V^T[d][phys(8c+e)] of the tile.
// perm within 32-block: pb -> (pb&3) + ((pb>>2)&1)*8 + ((pb>>3)&1)*4 + (pb&16)
__global__ __launch_bounds__(256)
void vtrans2(const __hip_bfloat16* __restrict__ qkv, __hip_bfloat16* __restrict__ Vt2) {
  __shared__ short L[64 * 65];  // [d_local][s_local]
  const int tid = threadIdx.x;
  const int t = blockIdx.x, d0 = blockIdx.y * 64, z = blockIdx.z;
  const int b = z >> 2, hkv = z & 3;
  const int s0 = t * 64;
#pragma unroll
  for (int i = 0; i < 2; ++i) {
    const int slot = i * 256 + tid;
    const int srow = slot >> 3, c8 = (slot & 7) * 8;
    const short8 v = *(const short8*)((const short*)qkv +
        (size_t)(b * 2048 + s0 + srow) * 3072 + 2560 + hkv * 128 + d0 + c8);
#pragma unroll
    for (int j = 0; j < 8; ++j) L[(c8 + j) * 65 + srow] = v[j];
  }
  __syncthreads();
  short* dst = (short*)Vt2 + (size_t)z * 262144 + t * 8192;
#pragma unroll
  for (int i = 0; i < 2; ++i) {
    const int slot = i * 256 + tid;
    const int drow = slot >> 3, sc8 = (slot & 7) * 8;
    short8 o;
#pragma unroll
    for (int j = 0; j < 8; ++j) {
      const int p = sc8 + j;
      const int pb = p & 31;
      const int phys = (p & ~31) | ((pb & 3) + ((pb >> 2) & 1) * 8 + ((pb >> 3) & 1) * 4 + (pb & 16));
      o[j] = L[drow * 65 + phys];
    }
    *(short8*)&dst[(sc8 >> 3) * 1024 + (d0 + drow) * 8] = o;
  }
}

// ---------------- Flash attention (non-causal, GQA 4:1), 32x32 MFMA, S^T form ----------------
// Cross-tile software pipeline: body u runs QK(u) || PV(u-1), exp(u) overlaps PV MFMAs.
// K double-buffered, V triple-buffered. exp2 with NO offset/scale math (Q pre-scaled;
// offset cancels in O = PV/l). l via ones-MFMA (perm-invariant). Zero-shuffle PV.
__global__ __launch_bounds__(256, 2)
void fattn(const __hip_bfloat16* __restrict__ Qg, const __hip_bfloat16* __restrict__ Kb2,
           const __hip_bfloat16* __restrict__ Vt2, __hip_bfloat16* __restrict__ Og) {
  __shared__ short SMEM[40960];  // Kb[2] @ 0,8192 | Vb[3] @ 16384,24576,32768 (80 KB)

  const int tid = threadIdx.x, wid = tid >> 6, lane = tid & 63;
  const int l31 = lane & 31, hi = lane >> 5;
  const int qt = blockIdx.x, bh = blockIdx.y;
  const int b = bh >> 4, h = bh & 15, hkv = h >> 2;
  const int z = b * 4 + hkv;
  const int q0w = qt * 128 + wid * 32;

  // Q as B-fragments for 32x32x16: B[k = hi*8+j][col = l31 -> q], k-step 16 over d
  const __hip_bfloat16* Qrow = Qg + ((size_t)((b * 16 + h) * 2048 + q0w + l31)) * 128;
  short8 qf2[8];
#pragma unroll
  for (int ks = 0; ks < 8; ++ks) qf2[ks] = *(const short8*)(Qrow + ks * 16 + hi * 8);

  const short* Kbase = (const short*)Kb2 + (size_t)z * 262144;
  const short* Vbase = (const short*)Vt2 + (size_t)z * 262144;

  auto stageK = [&](int buf, int t) {
    const short* ks = Kbase + t * 8192 + wid * 2048 + lane * 8;
    short* kd = &SMEM[buf * 8192 + wid * 2048];
#pragma unroll
    for (int i = 0; i < 4; ++i)
      gload_lds16((const __hip_bfloat16*)(ks + i * 512), (__hip_bfloat16*)(kd + i * 512));
  };
  auto stageV = [&](int slot, int t) {
    const short* vs = Vbase + t * 8192 + wid * 2048 + lane * 8;
    short* vd = &SMEM[16384 + slot * 8192 + wid * 2048];
#pragma unroll
    for (int i = 0; i < 4; ++i)
      gload_lds16((const __hip_bfloat16*)(vs + i * 512), (__hip_bfloat16*)(vd + i * 512));
  };

  // oacc[dblk]: O^T[d = dblk*32 + (reg&3)+8*(reg>>2)+4*hi][q = l31]; lacc = l replicated
  floatx16 oacc[4];
#pragma unroll
  for (int dblk = 0; dblk < 4; ++dblk) oacc[dblk] = (floatx16)(0.0f);
  floatx16 lacc = (floatx16)(0.0f);

  short8 ones;
#pragma unroll
  for (int j = 0; j < 8; ++j) ones[j] = (short)0x3F80;  // bf16 1.0

  int pkA[2][8], pkB[2][8];

  auto doQK = [&](int kbuf, floatx16 (&st)[2]) {
    const short* Kt = &SMEM[kbuf * 8192];
    st[0] = (floatx16)(0.0f);
    st[1] = (floatx16)(0.0f);
    __builtin_amdgcn_s_setprio(1);
#pragma unroll
    for (int ks = 0; ks < 8; ++ks) {
      const short8 kf0 = *(const short8*)&Kt[(ks * 2 + hi) * 512 + l31 * 8];
      const short8 kf1 = *(const short8*)&Kt[(ks * 2 + hi) * 512 + 256 + l31 * 8];
      st[0] = MFMA32(kf0, qf2[ks], st[0]);
      st[1] = MFMA32(kf1, qf2[ks], st[1]);
    }
    __builtin_amdgcn_s_setprio(0);
  };
  auto doExp = [&](const floatx16 (&st)[2], int (&pk)[2][8]) {
#pragma unroll
    for (int kvblk = 0; kvblk < 2; ++kvblk)
#pragma unroll
      for (int m = 0; m < 8; ++m) {
        const float e0 = exp2f(st[kvblk][2 * m]);
        const float e1 = exp2f(st[kvblk][2 * m + 1]);
        asm("v_cvt_pk_bf16_f32 %0, %1, %2" : "=v"(pk[kvblk][m]) : "v"(e0), "v"(e1));
      }
  };
  auto doPV = [&](int vslot, const int (&pk)[2][8]) {
    const short* Vt = &SMEM[16384 + vslot * 8192];
#pragma unroll
    for (int kvblk = 0; kvblk < 2; ++kvblk) {
#pragma unroll
      for (int s = 0; s < 2; ++s) {
        union { int i[4]; short8 s8; } u;
        u.i[0] = pk[kvblk][4 * s + 0];
        u.i[1] = pk[kvblk][4 * s + 1];
        u.i[2] = pk[kvblk][4 * s + 2];
        u.i[3] = pk[kvblk][4 * s + 3];
        const short8 pB = u.s8;
        const int c = kvblk * 4 + s * 2 + hi;
        __builtin_amdgcn_s_setprio(1);
        lacc = MFMA32(ones, pB, lacc);
#pragma unroll
        for (int dblk = 0; dblk < 4; ++dblk) {
          const short8 vf = *(const short8*)&Vt[c * 1024 + dblk * 256 + l31 * 8];
          oacc[dblk] = MFMA32(vf, pB, oacc[dblk]);
        }
        __builtin_amdgcn_s_setprio(0);
      }
    }
  };

  int vs_stage = 2, vs_pv = 0;
  // body u: stage(u+1); QK(u); PV(u-1) [pkPrev]; exp(u)->pkCur; fence
  auto body = [&](int (&pkPrev)[2][8], int (&pkCur)[2][8], int u) {
    if (u + 1 < 32) {
      stageK((u + 1) & 1, u + 1);
      stageV(vs_stage, u + 1);
    }
    floatx16 st[2];
    doQK(u & 1, st);
    doPV(vs_pv, pkPrev);
    doExp(st, pkCur);
    vs_stage = (vs_stage == 2) ? 0 : vs_stage + 1;
    vs_pv = (vs_pv == 2) ? 0 : vs_pv + 1;
    asm volatile("s_waitcnt vmcnt(0)" ::: "memory");
    __builtin_amdgcn_s_barrier();
    __builtin_amdgcn_sched_barrier(0);
  };

  // prologue: tile 0 staged, then body 0 (no PV)
  stageK(0, 0);
  stageV(0, 0);
  asm volatile("s_waitcnt vmcnt(0)" ::: "memory");
  __builtin_amdgcn_s_barrier();
  __builtin_amdgcn_sched_barrier(0);
  {
    stageK(1, 1);
    stageV(1, 1);
    floatx16 st[2];
    doQK(0, st);
    doExp(st, pkA);
    asm volatile("s_waitcnt vmcnt(0)" ::: "memory");
    __builtin_amdgcn_s_barrier();
    __builtin_amdgcn_sched_barrier(0);
  }

  for (int u = 1; u < 31; u += 2) {
    body(pkA, pkB, u);
    body(pkB, pkA, u + 1);
  }
  body(pkA, pkB, 31);   // QK(31), PV(30), exp(31)->pkB
  doPV(vs_pv, pkB);     // PV(31)

  // all waves done with LDS before tw overwrites it
  asm volatile("s_waitcnt lgkmcnt(0)" ::: "memory");
  __builtin_amdgcn_s_barrier();

  // epilogue: normalize by l (= lacc[0], no shuffles); LDS transpose; coalesced store
  const float inv = 1.0f / lacc[0];
  short* tw = &SMEM[wid * 4352];  // [32 q][136 d-padded]
#pragma unroll
  for (int dblk = 0; dblk < 4; ++dblk)
#pragma unroll
    for (int a = 0; a < 4; ++a) {
      __hip_bfloat16 o4[4];
#pragma unroll
      for (int r = 0; r < 4; ++r) o4[r] = __float2bfloat16(oacc[dblk][4 * a + r] * inv);
      *(short4*)&tw[l31 * 136 + dblk * 32 + a * 8 + hi * 4] = *(const short4*)o4;
    }
  __hip_bfloat16* orow =
      Og + ((size_t)(b * 2048 + q0w + (lane >> 1))) * 2048 + h * 128 + (lane & 1) * 64;
  const short* trow = &tw[(lane >> 1) * 136 + (lane & 1) * 64];
#pragma unroll
  for (int c = 0; c < 8; ++c) {
    *(short8*)(orow + c * 8) = *(const short8*)(trow + c * 8);
  }
}

// ---------------- launch ----------------
extern "C" void kernel_launch(void* const* d_in, const int* in_sizes, int n_in,
                              void* d_out, int out_size, void* d_ws, size_t ws_size,
                              hipStream_t stream) {
  const float* hidden = (const float*)d_in[0];
  const float* cosb = (const float*)d_in[1];
  const float* sinb = (const float*)d_in[2];
  const float* Wq = (const float*)d_in[3];
  const float* Wk = (const float*)d_in[4];
  const float* Wv = (const float*)d_in[5];
  const float* Wo = (const float*)d_in[6];
  const float* qw = (const float*)d_in[7];
  const float* kw = (const float*)d_in[8];

  char* ws = (char*)d_ws;
  __hip_bfloat16* hidden_bf = (__hip_bfloat16*)ws; ws += (size_t)4096 * 2048 * 2;
  __hip_bfloat16* wqkv = (__hip_bfloat16*)ws;      ws += (size_t)3072 * 2048 * 2;
  __hip_bfloat16* wo_bf = (__hip_bfloat16*)ws;     ws += (size_t)2048 * 2048 * 2;
  __hip_bfloat16* qkv = (__hip_bfloat16*)ws;       ws += (size_t)4096 * 3072 * 2;
  __hip_bfloat16* Qb = (__hip_bfloat16*)ws;        ws += (size_t)2 * 16 * 2048 * 128 * 2;
  __hip_bfloat16* Kblk = (__hip_bfloat16*)ws;      ws += (size_t)2 * 4 * 2048 * 128 * 2;
  __hip_bfloat16* attn = (__hip_bfloat16*)ws;      ws += (size_t)4096 * 2048 * 2;
  // Vt2 aliases wqkv (dead after gemm1; rewritten by f2bf_all every call -> deterministic)
  __hip_bfloat16* Vt2 = wqkv;

  f2bf_all<<<18432, 256, 0, stream>>>(hidden, Wq, Wk, Wv, Wo, hidden_bf, wqkv, wo_bf);

  gemm_bt<__hip_bfloat16><<<dim3(32, 24), 256, 0, stream>>>(hidden_bf, wqkv, qkv, 4096, 3072, 2048);
  normrope<<<4096, 256, 0, stream>>>(qkv, cosb, sinb, qw, kw, Qb, Kblk);
  vtrans2<<<dim3(32, 2, 8), 256, 0, stream>>>(qkv, Vt2);
  fattn<<<dim3(16, 32), 256, 0, stream>>>(Qb, Kblk, Vt2, attn);
  gemm_bt<float><<<dim3(32, 16), 256, 0, stream>>>(attn, wo_bf, (float*)d_out, 4096, 2048, 2048);
}